// Round 13
// baseline (430.293 us; speedup 1.0000x reference)
//
#include <hip/hip_runtime.h>
#include <hip/hip_bf16.h>
#include <hip/hip_fp16.h>

#define T_DIM 2048
#define B_DIM 32
#define LIS_DIM 1024
#define SPE_DIM 1024
#define ATT_DIM 512

typedef _Float16 f16x8 __attribute__((ext_vector_type(8)));
typedef _Float16 f16x4 __attribute__((ext_vector_type(4)));
typedef float f32x4 __attribute__((ext_vector_type(4)));

// K0: prep. Blocks 0..63: pack W into MFMA-fragment order
//   WTf_f16x8[((mat*32+ct)*32+ks)*64 + lane] : h[j] = W[ks*32+hi*8+j][ct*16+lo]
// Blocks 64..95: q[b][a] = relu(spe[b]·W_proj[:,a] + b_proj[a])
__global__ __launch_bounds__(256)
void prep_kernel(const float* __restrict__ Ws,
                 const float* __restrict__ Wv,
                 _Float16* __restrict__ WTf,
                 const float* __restrict__ spe,
                 const float* __restrict__ Wp,
                 const float* __restrict__ bp,
                 float* __restrict__ q) {
  int blk = blockIdx.x;
  int tid = threadIdx.x;
  if (blk < 64) {
    __shared__ float t17[1024 * 17];
    int mat = blk >> 5, ct = blk & 31;
    const float* W = mat ? Wv : Ws;
    for (int e = tid; e < 16384; e += 256) {
      int k = e >> 4, c = e & 15;
      t17[k * 17 + c] = W[(size_t)k * ATT_DIM + ct * 16 + c];
    }
    __syncthreads();
    int wv4 = tid >> 6, lane = tid & 63, lo = lane & 15, hi = lane >> 4;
    for (int ks = wv4; ks < 32; ks += 4) {
      f16x8 h;
#pragma unroll
      for (int j = 0; j < 8; ++j)
        h[j] = (_Float16)t17[(ks * 32 + hi * 8 + j) * 17 + lo];
      ((f16x8*)WTf)[((size_t)((mat * 32 + ct) * 32 + ks)) * 64 + lane] = h;
    }
  } else {
    __shared__ float s[SPE_DIM];
    int b = blk - 64;
    for (int i = tid; i < SPE_DIM; i += 256) s[i] = spe[(size_t)b * SPE_DIM + i];
    __syncthreads();
    for (int a = tid; a < ATT_DIM; a += 256) {
      float acc = bp[a];
      for (int l = 0; l < SPE_DIM; ++l)
        acc = fmaf(s[l], Wp[(size_t)l * ATT_DIM + a], acc);
      q[(size_t)b * ATT_DIM + a] = fmaxf(acc, 0.f);
    }
  }
}

// K1: dual GEMM, M=64 (one b, 64 t's), BK=256 (4 chunks, 4 barriers total).
// x staged via NT loads (keep W L2-resident); vals written NT packed.
__global__ __launch_bounds__(512, 2)
void dual_gemm_kernel(const float* __restrict__ x,
                      const _Float16* __restrict__ WTf,
                      const float* __restrict__ bs,
                      const float* __restrict__ bv,
                      const float* __restrict__ q,
                      float* __restrict__ scores,
                      _Float16* __restrict__ vals_p) {
  __shared__ __align__(16) char A_lds[2][32768];  // 64 rows x 256k f16, XOR swz
  __shared__ float bk_s[ATT_DIM], bv_s[ATT_DIM], q_s[ATT_DIM];
  __shared__ float red_s[64];

  const int tid = threadIdx.x;
  const int blk = blockIdx.x;
  const int b = blk & 31;
  const int tc = blk >> 5;
  const int t0 = tc * 64;

  bk_s[tid] = bs[tid];
  bv_s[tid] = bv[tid];
  q_s[tid] = q[(size_t)b * ATT_DIM + tid];
  if (tid < 64) red_s[tid] = 0.f;

  const float* xb = x + (size_t)b * LIS_DIM;
  const int wv = tid >> 6;
  const int lane = tid & 63;
  const int lo = lane & 15;
  const int hi = lane >> 4;

  f32x4 sl[8];  // in-flight stage registers (one chunk = 256 k)
  auto stage_load = [&](int c) {
    const int k0 = c * 256;
#pragma unroll
    for (int it = 0; it < 8; ++it) {
      int idx = it * 512 + tid;     // 4096 f32x4 = 64 rows x 64
      int row = idx >> 6;
      int c4 = idx & 63;
      sl[it] = __builtin_nontemporal_load(
          (const f32x4*)(xb + (size_t)(t0 + row) * (B_DIM * LIS_DIM) + k0) + c4);
    }
  };
  auto stage_write = [&](int c) {
    char* buf = A_lds[c & 1];
#pragma unroll
    for (int it = 0; it < 8; ++it) {
      int idx = it * 512 + tid;
      int row = idx >> 6;
      int c4 = idx & 63;
      f16x4 h;
      h[0] = (_Float16)sl[it][0]; h[1] = (_Float16)sl[it][1];
      h[2] = (_Float16)sl[it][2]; h[3] = (_Float16)sl[it][3];
      int off = (row * 512 + c4 * 8) ^ ((row & 7) << 4);
      *(f16x4*)(buf + off) = h;
    }
  };

  f32x4 kacc[4][4], vacc[4][4];
#pragma unroll
  for (int m = 0; m < 4; ++m)
#pragma unroll
    for (int n = 0; n < 4; ++n) {
      kacc[m][n] = (f32x4){0.f, 0.f, 0.f, 0.f};
      vacc[m][n] = (f32x4){0.f, 0.f, 0.f, 0.f};
    }

  stage_load(0);
  stage_write(0);
  __syncthreads();

  const f16x8* Wf = (const f16x8*)WTf;

  for (int c = 0; c < 4; ++c) {
    if (c < 3) stage_load(c + 1);
    const char* buf = A_lds[c & 1];
#pragma unroll
    for (int kki = 0; kki < 8; ++kki) {
      const int ks = c * 8 + kki;
      const int kk = kki * 32;
      f16x8 wkf[4], wvf[4], bx[4];
#pragma unroll
      for (int n = 0; n < 4; ++n) {
        wkf[n] = Wf[(size_t)((wv * 4 + n) * 32 + ks) * 64 + lane];
        wvf[n] = Wf[(size_t)((32 + wv * 4 + n) * 32 + ks) * 64 + lane];
      }
#pragma unroll
      for (int m = 0; m < 4; ++m) {
        int row = m * 16 + lo;
        int off = (row * 512 + kk * 2 + hi * 16) ^ ((row & 7) << 4);
        bx[m] = *(const f16x8*)(buf + off);
      }
#pragma unroll
      for (int n = 0; n < 4; ++n)
#pragma unroll
        for (int m = 0; m < 4; ++m) {
          kacc[m][n] = __builtin_amdgcn_mfma_f32_16x16x32_f16(wkf[n], bx[m], kacc[m][n], 0, 0, 0);
          vacc[m][n] = __builtin_amdgcn_mfma_f32_16x16x32_f16(wvf[n], bx[m], vacc[m][n], 0, 0, 0);
        }
    }
    if (c < 3) stage_write(c + 1);
    __syncthreads();
  }

  // vals epilogue: packed lane-natural layout, non-temporal 8B stores
  _Float16* vp = vals_p + ((size_t)(b * 32 + tc) * 8 + wv) * 4096;
#pragma unroll
  for (int m = 0; m < 4; ++m)
#pragma unroll
    for (int n = 0; n < 4; ++n) {
      int col = wv * 64 + n * 16 + hi * 4;
      f16x4 h;
#pragma unroll
      for (int r = 0; r < 4; ++r)
        h[r] = (_Float16)fmaxf(vacc[m][n][r] + bv_s[col + r], 0.f);
      __builtin_nontemporal_store(h, (f16x4*)(vp + (m * 4 + n) * 256 + lane * 4));
    }

  // scores epilogue
  float sr[4] = {0.f, 0.f, 0.f, 0.f};
#pragma unroll
  for (int m = 0; m < 4; ++m)
#pragma unroll
    for (int n = 0; n < 4; ++n) {
      int col = wv * 64 + n * 16 + hi * 4;
#pragma unroll
      for (int r = 0; r < 4; ++r)
        sr[m] += q_s[col + r] * fmaxf(kacc[m][n][r] + bk_s[col + r], 0.f);
    }
#pragma unroll
  for (int m = 0; m < 4; ++m) {
    sr[m] += __shfl_xor(sr[m], 16, 64);
    sr[m] += __shfl_xor(sr[m], 32, 64);
    if (lane < 16) atomicAdd(&red_s[m * 16 + lo], sr[m]);
  }
  __syncthreads();
  if (tid < 64) scores[(size_t)b * T_DIM + t0 + tid] = red_s[tid];
}

// K2: masked softmax per b; writes attn f32 to out, zeroes context region of out
__global__ void softmax_kernel(const float* __restrict__ scores,
                               const int* __restrict__ llen,
                               float* __restrict__ attn_out,   // d_out + 16384
                               float* __restrict__ ctx_out) {  // d_out (zeroed here)
  __shared__ float rmax[4], rsum[4];
  int b = blockIdx.x, tid = threadIdx.x;
  int L = llen[b];
  float v[8];
  float mx = -1e30f;
  for (int i = 0; i < 8; ++i) {
    int t = i * 256 + tid;
    float s = scores[(size_t)b * T_DIM + t];
    if (t >= L) s -= 100.f;
    v[i] = s;
    mx = fmaxf(mx, s);
  }
  for (int d = 1; d < 64; d <<= 1) mx = fmaxf(mx, __shfl_xor(mx, d, 64));
  if ((tid & 63) == 0) rmax[tid >> 6] = mx;
  __syncthreads();
  mx = fmaxf(fmaxf(rmax[0], rmax[1]), fmaxf(rmax[2], rmax[3]));
  float sum = 0.f;
  for (int i = 0; i < 8; ++i) { v[i] = expf(v[i] - mx); sum += v[i]; }
  for (int d = 1; d < 64; d <<= 1) sum += __shfl_xor(sum, d, 64);
  if ((tid & 63) == 0) rsum[tid >> 6] = sum;
  __syncthreads();
  sum = rsum[0] + rsum[1] + rsum[2] + rsum[3];
  float inv = 1.f / sum;
  for (int i = 0; i < 8; ++i) {
    int t = i * 256 + tid;
    attn_out[(size_t)b * T_DIM + t] = v[i] * inv;
  }
  for (int i = tid; i < ATT_DIM; i += 256) ctx_out[(size_t)b * ATT_DIM + i] = 0.f;
}

// K3: ctx[b][col] = sum_t attn[b][t] * vals[t][col], decoding packed layout.
__global__ __launch_bounds__(512)
void ctx_kernel(const _Float16* __restrict__ vals_p,
                const float* __restrict__ attn,
                float* __restrict__ ctx) {
  __shared__ float attn_s[256];
  int blk = blockIdx.x;
  int b = blk >> 3, tcg = blk & 7;
  int tid = threadIdx.x;
  int wv = tid >> 6, lane = tid & 63, lo = lane & 15, hi = lane >> 4;
  if (tid < 256) attn_s[tid] = attn[(size_t)b * T_DIM + tcg * 256 + tid];
  __syncthreads();
  float cacc[4][4] = {};
  for (int i = 0; i < 4; ++i) {
    int tc = tcg * 4 + i;
    const _Float16* vp = vals_p + ((size_t)(b * 32 + tc) * 8 + wv) * 4096;
#pragma unroll
    for (int m = 0; m < 4; ++m) {
      float w = attn_s[i * 64 + m * 16 + lo];
#pragma unroll
      for (int n = 0; n < 4; ++n) {
        f16x4 v = __builtin_nontemporal_load(
            (const f16x4*)(vp + (m * 4 + n) * 256 + lane * 4));
#pragma unroll
        for (int r = 0; r < 4; ++r) cacc[n][r] += w * (float)v[r];
      }
    }
  }
#pragma unroll
  for (int n = 0; n < 4; ++n)
#pragma unroll
    for (int r = 0; r < 4; ++r) {
      float v = cacc[n][r];
      v += __shfl_xor(v, 1, 64);
      v += __shfl_xor(v, 2, 64);
      v += __shfl_xor(v, 4, 64);
      v += __shfl_xor(v, 8, 64);
      if (lo == 0)
        atomicAdd(&ctx[(size_t)b * ATT_DIM + wv * 64 + n * 16 + hi * 4 + r], v);
    }
}

extern "C" void kernel_launch(void* const* d_in, const int* in_sizes, int n_in,
                              void* d_out, int out_size, void* d_ws, size_t ws_size,
                              hipStream_t stream) {
  const float* x   = (const float*)d_in[0];
  const float* spe = (const float*)d_in[1];
  const int*   len = (const int*)d_in[2];
  const float* Ws  = (const float*)d_in[4];
  const float* bs  = (const float*)d_in[5];
  const float* Wv  = (const float*)d_in[6];
  const float* bv  = (const float*)d_in[7];
  const float* Wp  = (const float*)d_in[8];
  const float* bp  = (const float*)d_in[9];
  float* out = (float*)d_out;  // [0,16384): context f32, [16384,81920): attn f32

  char* ws = (char*)d_ws;
  _Float16* WTf  = (_Float16*)ws;                            // 2 MB packed frags
  float* q       = (float*)(ws + (2u << 20));                // 64 KB
  float* scores  = (float*)(ws + (2u << 20) + (64u << 10));  // 256 KB
  _Float16* vals = (_Float16*)(ws + (4u << 20));             // 64 MB packed

  prep_kernel<<<dim3(96), dim3(256), 0, stream>>>(Ws, Wv, WTf, spe, Wp, bp, q);
  dual_gemm_kernel<<<dim3(1024), dim3(512), 0, stream>>>(
      x, WTf, bs, bv, q, scores, vals);
  softmax_kernel<<<dim3(32), dim3(256), 0, stream>>>(scores, len, out + 16384, out);
  ctx_kernel<<<dim3(256), dim3(512), 0, stream>>>(vals, out + 16384, out);
}

// Round 14
// 330.149 us; speedup vs baseline: 1.3033x; 1.3033x over previous
//
#include <hip/hip_runtime.h>
#include <hip/hip_bf16.h>
#include <hip/hip_fp16.h>

#define T_DIM 2048
#define B_DIM 32
#define LIS_DIM 1024
#define SPE_DIM 1024
#define ATT_DIM 512

typedef _Float16 f16x8 __attribute__((ext_vector_type(8)));
typedef _Float16 f16x4 __attribute__((ext_vector_type(4)));
typedef float f32x4 __attribute__((ext_vector_type(4)));

// K0: prep. Blocks 0..63: pack W into MFMA-fragment order
//   WTf_f16x8[((mat*32+ct)*32+ks)*64 + lane] : h[j] = W[ks*32+hi*8+j][ct*16+lo]
// Blocks 64..95: q[b][a] = relu(spe[b]·W_proj[:,a] + b_proj[a])
__global__ __launch_bounds__(256)
void prep_kernel(const float* __restrict__ Ws,
                 const float* __restrict__ Wv,
                 _Float16* __restrict__ WTf,
                 const float* __restrict__ spe,
                 const float* __restrict__ Wp,
                 const float* __restrict__ bp,
                 float* __restrict__ q) {
  int blk = blockIdx.x;
  int tid = threadIdx.x;
  if (blk < 64) {
    __shared__ float t17[1024 * 17];
    int mat = blk >> 5, ct = blk & 31;
    const float* W = mat ? Wv : Ws;
    for (int e = tid; e < 16384; e += 256) {
      int k = e >> 4, c = e & 15;
      t17[k * 17 + c] = W[(size_t)k * ATT_DIM + ct * 16 + c];
    }
    __syncthreads();
    int wv4 = tid >> 6, lane = tid & 63, lo = lane & 15, hi = lane >> 4;
    for (int ks = wv4; ks < 32; ks += 4) {
      f16x8 h;
#pragma unroll
      for (int j = 0; j < 8; ++j)
        h[j] = (_Float16)t17[(ks * 32 + hi * 8 + j) * 17 + lo];
      ((f16x8*)WTf)[((size_t)((mat * 32 + ct) * 32 + ks)) * 64 + lane] = h;
    }
  } else {
    __shared__ float s[SPE_DIM];
    int b = blk - 64;
    for (int i = tid; i < SPE_DIM; i += 256) s[i] = spe[(size_t)b * SPE_DIM + i];
    __syncthreads();
    for (int a = tid; a < ATT_DIM; a += 256) {
      float acc = bp[a];
      for (int l = 0; l < SPE_DIM; ++l)
        acc = fmaf(s[l], Wp[(size_t)l * ATT_DIM + a], acc);
      q[(size_t)b * ATT_DIM + a] = fmaxf(acc, 0.f);
    }
  }
}

// K1: dual GEMM, M=64 (one b, 64 t's), BK=256 (4 chunks, 4 barriers).
// Staging split into two register-disjoint row-halves (1KB DRAM granules,
// sl[4]=16 VGPR each, short lifetimes -> no spill).
__global__ __launch_bounds__(512, 2)
void dual_gemm_kernel(const float* __restrict__ x,
                      const _Float16* __restrict__ WTf,
                      const float* __restrict__ bs,
                      const float* __restrict__ bv,
                      const float* __restrict__ q,
                      float* __restrict__ scores,
                      _Float16* __restrict__ vals_p) {
  __shared__ __align__(16) char A_lds[2][32768];  // 64 rows x 256k f16, XOR swz
  __shared__ float bk_s[ATT_DIM], bv_s[ATT_DIM], q_s[ATT_DIM];
  __shared__ float red_s[64];

  const int tid = threadIdx.x;
  const int blk = blockIdx.x;
  const int b = blk & 31;
  const int tc = blk >> 5;
  const int t0 = tc * 64;

  bk_s[tid] = bs[tid];
  bv_s[tid] = bv[tid];
  q_s[tid] = q[(size_t)b * ATT_DIM + tid];
  if (tid < 64) red_s[tid] = 0.f;

  const float* xb = x + (size_t)b * LIS_DIM;
  const int wv = tid >> 6;
  const int lane = tid & 63;
  const int lo = lane & 15;
  const int hi = lane >> 4;

  f32x4 sl[4];  // staging regs, reused by both row-halves (disjoint lifetimes)
  // half h: rows [h*32, h*32+32), full BK=256 -> 1KB contiguous per row
  auto stage_load = [&](int c, int h) {
    const int k0 = c * 256;
#pragma unroll
    for (int it = 0; it < 4; ++it) {
      int idx = (h * 4 + it) * 512 + tid;   // 2048 f32x4 per half
      int row = idx >> 6;
      int c4 = idx & 63;
      sl[it] = __builtin_nontemporal_load(
          (const f32x4*)(xb + (size_t)(t0 + row) * (B_DIM * LIS_DIM) + k0) + c4);
    }
  };
  auto stage_write = [&](int c, int h) {
    char* buf = A_lds[c & 1];
#pragma unroll
    for (int it = 0; it < 4; ++it) {
      int idx = (h * 4 + it) * 512 + tid;
      int row = idx >> 6;
      int c4 = idx & 63;
      f16x4 hh;
      hh[0] = (_Float16)sl[it][0]; hh[1] = (_Float16)sl[it][1];
      hh[2] = (_Float16)sl[it][2]; hh[3] = (_Float16)sl[it][3];
      int off = (row * 512 + c4 * 8) ^ ((row & 7) << 4);
      *(f16x4*)(buf + off) = hh;
    }
  };

  f32x4 kacc[4][4], vacc[4][4];
#pragma unroll
  for (int m = 0; m < 4; ++m)
#pragma unroll
    for (int n = 0; n < 4; ++n) {
      kacc[m][n] = (f32x4){0.f, 0.f, 0.f, 0.f};
      vacc[m][n] = (f32x4){0.f, 0.f, 0.f, 0.f};
    }

  stage_load(0, 0); stage_write(0, 0);
  stage_load(0, 1); stage_write(0, 1);
  __syncthreads();

  const f16x8* Wf = (const f16x8*)WTf;

  for (int c = 0; c < 4; ++c) {
    const char* buf = A_lds[c & 1];
    if (c < 3) stage_load(c + 1, 0);
    // first half-chunk: kki 0..3
#pragma unroll
    for (int kki = 0; kki < 4; ++kki) {
      const int ks = c * 8 + kki;
      const int kk = kki * 32;
      f16x8 wkf[4], wvf[4], bx[4];
#pragma unroll
      for (int n = 0; n < 4; ++n) {
        wkf[n] = Wf[(size_t)((wv * 4 + n) * 32 + ks) * 64 + lane];
        wvf[n] = Wf[(size_t)((32 + wv * 4 + n) * 32 + ks) * 64 + lane];
      }
#pragma unroll
      for (int m = 0; m < 4; ++m) {
        int row = m * 16 + lo;
        int off = (row * 512 + kk * 2 + hi * 16) ^ ((row & 7) << 4);
        bx[m] = *(const f16x8*)(buf + off);
      }
#pragma unroll
      for (int n = 0; n < 4; ++n)
#pragma unroll
        for (int m = 0; m < 4; ++m) {
          kacc[m][n] = __builtin_amdgcn_mfma_f32_16x16x32_f16(wkf[n], bx[m], kacc[m][n], 0, 0, 0);
          vacc[m][n] = __builtin_amdgcn_mfma_f32_16x16x32_f16(wvf[n], bx[m], vacc[m][n], 0, 0, 0);
        }
    }
    if (c < 3) { stage_write(c + 1, 0); stage_load(c + 1, 1); }
    // second half-chunk: kki 4..7
#pragma unroll
    for (int kki = 4; kki < 8; ++kki) {
      const int ks = c * 8 + kki;
      const int kk = kki * 32;
      f16x8 wkf[4], wvf[4], bx[4];
#pragma unroll
      for (int n = 0; n < 4; ++n) {
        wkf[n] = Wf[(size_t)((wv * 4 + n) * 32 + ks) * 64 + lane];
        wvf[n] = Wf[(size_t)((32 + wv * 4 + n) * 32 + ks) * 64 + lane];
      }
#pragma unroll
      for (int m = 0; m < 4; ++m) {
        int row = m * 16 + lo;
        int off = (row * 512 + kk * 2 + hi * 16) ^ ((row & 7) << 4);
        bx[m] = *(const f16x8*)(buf + off);
      }
#pragma unroll
      for (int n = 0; n < 4; ++n)
#pragma unroll
        for (int m = 0; m < 4; ++m) {
          kacc[m][n] = __builtin_amdgcn_mfma_f32_16x16x32_f16(wkf[n], bx[m], kacc[m][n], 0, 0, 0);
          vacc[m][n] = __builtin_amdgcn_mfma_f32_16x16x32_f16(wvf[n], bx[m], vacc[m][n], 0, 0, 0);
        }
    }
    if (c < 3) stage_write(c + 1, 1);
    __syncthreads();
  }

  // vals epilogue: packed lane-natural layout, non-temporal 8B stores
  _Float16* vp = vals_p + ((size_t)(b * 32 + tc) * 8 + wv) * 4096;
#pragma unroll
  for (int m = 0; m < 4; ++m)
#pragma unroll
    for (int n = 0; n < 4; ++n) {
      int col = wv * 64 + n * 16 + hi * 4;
      f16x4 h;
#pragma unroll
      for (int r = 0; r < 4; ++r)
        h[r] = (_Float16)fmaxf(vacc[m][n][r] + bv_s[col + r], 0.f);
      __builtin_nontemporal_store(h, (f16x4*)(vp + (m * 4 + n) * 256 + lane * 4));
    }

  // scores epilogue
  float sr[4] = {0.f, 0.f, 0.f, 0.f};
#pragma unroll
  for (int m = 0; m < 4; ++m)
#pragma unroll
    for (int n = 0; n < 4; ++n) {
      int col = wv * 64 + n * 16 + hi * 4;
#pragma unroll
      for (int r = 0; r < 4; ++r)
        sr[m] += q_s[col + r] * fmaxf(kacc[m][n][r] + bk_s[col + r], 0.f);
    }
#pragma unroll
  for (int m = 0; m < 4; ++m) {
    sr[m] += __shfl_xor(sr[m], 16, 64);
    sr[m] += __shfl_xor(sr[m], 32, 64);
    if (lane < 16) atomicAdd(&red_s[m * 16 + lo], sr[m]);
  }
  __syncthreads();
  if (tid < 64) scores[(size_t)b * T_DIM + t0 + tid] = red_s[tid];
}

// K2: masked softmax per b; writes attn f32 to out, zeroes context region of out
__global__ void softmax_kernel(const float* __restrict__ scores,
                               const int* __restrict__ llen,
                               float* __restrict__ attn_out,   // d_out + 16384
                               float* __restrict__ ctx_out) {  // d_out (zeroed here)
  __shared__ float rmax[4], rsum[4];
  int b = blockIdx.x, tid = threadIdx.x;
  int L = llen[b];
  float v[8];
  float mx = -1e30f;
  for (int i = 0; i < 8; ++i) {
    int t = i * 256 + tid;
    float s = scores[(size_t)b * T_DIM + t];
    if (t >= L) s -= 100.f;
    v[i] = s;
    mx = fmaxf(mx, s);
  }
  for (int d = 1; d < 64; d <<= 1) mx = fmaxf(mx, __shfl_xor(mx, d, 64));
  if ((tid & 63) == 0) rmax[tid >> 6] = mx;
  __syncthreads();
  mx = fmaxf(fmaxf(rmax[0], rmax[1]), fmaxf(rmax[2], rmax[3]));
  float sum = 0.f;
  for (int i = 0; i < 8; ++i) { v[i] = expf(v[i] - mx); sum += v[i]; }
  for (int d = 1; d < 64; d <<= 1) sum += __shfl_xor(sum, d, 64);
  if ((tid & 63) == 0) rsum[tid >> 6] = sum;
  __syncthreads();
  sum = rsum[0] + rsum[1] + rsum[2] + rsum[3];
  float inv = 1.f / sum;
  for (int i = 0; i < 8; ++i) {
    int t = i * 256 + tid;
    attn_out[(size_t)b * T_DIM + t] = v[i] * inv;
  }
  for (int i = tid; i < ATT_DIM; i += 256) ctx_out[(size_t)b * ATT_DIM + i] = 0.f;
}

// K3: ctx[b][col] = sum_t attn[b][t] * vals[t][col], decoding packed layout.
__global__ __launch_bounds__(512)
void ctx_kernel(const _Float16* __restrict__ vals_p,
                const float* __restrict__ attn,
                float* __restrict__ ctx) {
  __shared__ float attn_s[256];
  int blk = blockIdx.x;
  int b = blk >> 3, tcg = blk & 7;
  int tid = threadIdx.x;
  int wv = tid >> 6, lane = tid & 63, lo = lane & 15, hi = lane >> 4;
  if (tid < 256) attn_s[tid] = attn[(size_t)b * T_DIM + tcg * 256 + tid];
  __syncthreads();
  float cacc[4][4] = {};
  for (int i = 0; i < 4; ++i) {
    int tc = tcg * 4 + i;
    const _Float16* vp = vals_p + ((size_t)(b * 32 + tc) * 8 + wv) * 4096;
#pragma unroll
    for (int m = 0; m < 4; ++m) {
      float w = attn_s[i * 64 + m * 16 + lo];
#pragma unroll
      for (int n = 0; n < 4; ++n) {
        f16x4 v = __builtin_nontemporal_load(
            (const f16x4*)(vp + (m * 4 + n) * 256 + lane * 4));
#pragma unroll
        for (int r = 0; r < 4; ++r) cacc[n][r] += w * (float)v[r];
      }
    }
  }
#pragma unroll
  for (int n = 0; n < 4; ++n)
#pragma unroll
    for (int r = 0; r < 4; ++r) {
      float v = cacc[n][r];
      v += __shfl_xor(v, 1, 64);
      v += __shfl_xor(v, 2, 64);
      v += __shfl_xor(v, 4, 64);
      v += __shfl_xor(v, 8, 64);
      if (lo == 0)
        atomicAdd(&ctx[(size_t)b * ATT_DIM + wv * 64 + n * 16 + hi * 4 + r], v);
    }
}

extern "C" void kernel_launch(void* const* d_in, const int* in_sizes, int n_in,
                              void* d_out, int out_size, void* d_ws, size_t ws_size,
                              hipStream_t stream) {
  const float* x   = (const float*)d_in[0];
  const float* spe = (const float*)d_in[1];
  const int*   len = (const int*)d_in[2];
  const float* Ws  = (const float*)d_in[4];
  const float* bs  = (const float*)d_in[5];
  const float* Wv  = (const float*)d_in[6];
  const float* bv  = (const float*)d_in[7];
  const float* Wp  = (const float*)d_in[8];
  const float* bp  = (const float*)d_in[9];
  float* out = (float*)d_out;  // [0,16384): context f32, [16384,81920): attn f32

  char* ws = (char*)d_ws;
  _Float16* WTf  = (_Float16*)ws;                            // 2 MB packed frags
  float* q       = (float*)(ws + (2u << 20));                // 64 KB
  float* scores  = (float*)(ws + (2u << 20) + (64u << 10));  // 256 KB
  _Float16* vals = (_Float16*)(ws + (4u << 20));             // 64 MB packed

  prep_kernel<<<dim3(96), dim3(256), 0, stream>>>(Ws, Wv, WTf, spe, Wp, bp, q);
  dual_gemm_kernel<<<dim3(1024), dim3(512), 0, stream>>>(
      x, WTf, bs, bv, q, scores, vals);
  softmax_kernel<<<dim3(32), dim3(256), 0, stream>>>(scores, len, out + 16384, out);
  ctx_kernel<<<dim3(256), dim3(512), 0, stream>>>(vals, out + 16384, out);
}

// Round 15
// 258.230 us; speedup vs baseline: 1.6663x; 1.2785x over previous
//
#include <hip/hip_runtime.h>
#include <hip/hip_bf16.h>
#include <hip/hip_fp16.h>

#define T_DIM 2048
#define B_DIM 32
#define LIS_DIM 1024
#define SPE_DIM 1024
#define ATT_DIM 512

typedef _Float16 f16x8 __attribute__((ext_vector_type(8)));
typedef _Float16 f16x4 __attribute__((ext_vector_type(4)));
typedef float f32x4 __attribute__((ext_vector_type(4)));

// K0: prep. Blocks 0..63: pack W into MFMA-fragment order
//   WTf_f16x8[((mat*32+ct)*32+ks)*64 + lane] : h[j] = W[ks*32+hi*8+j][ct*16+lo]
// Blocks 64..95: q[b][a] = relu(spe[b]·W_proj[:,a] + b_proj[a])
__global__ __launch_bounds__(256)
void prep_kernel(const float* __restrict__ Ws,
                 const float* __restrict__ Wv,
                 _Float16* __restrict__ WTf,
                 const float* __restrict__ spe,
                 const float* __restrict__ Wp,
                 const float* __restrict__ bp,
                 float* __restrict__ q) {
  int blk = blockIdx.x;
  int tid = threadIdx.x;
  if (blk < 64) {
    __shared__ float t17[1024 * 17];
    int mat = blk >> 5, ct = blk & 31;
    const float* W = mat ? Wv : Ws;
    for (int e = tid; e < 16384; e += 256) {
      int k = e >> 4, c = e & 15;
      t17[k * 17 + c] = W[(size_t)k * ATT_DIM + ct * 16 + c];
    }
    __syncthreads();
    int wv4 = tid >> 6, lane = tid & 63, lo = lane & 15, hi = lane >> 4;
    for (int ks = wv4; ks < 32; ks += 4) {
      f16x8 h;
#pragma unroll
      for (int j = 0; j < 8; ++j)
        h[j] = (_Float16)t17[(ks * 32 + hi * 8 + j) * 17 + lo];
      ((f16x8*)WTf)[((size_t)((mat * 32 + ct) * 32 + ks)) * 64 + lane] = h;
    }
  } else {
    __shared__ float s[SPE_DIM];
    int b = blk - 64;
    for (int i = tid; i < SPE_DIM; i += 256) s[i] = spe[(size_t)b * SPE_DIM + i];
    __syncthreads();
    for (int a = tid; a < ATT_DIM; a += 256) {
      float acc = bp[a];
      for (int l = 0; l < SPE_DIM; ++l)
        acc = fmaf(s[l], Wp[(size_t)l * ATT_DIM + a], acc);
      q[(size_t)b * ATT_DIM + a] = fmaxf(acc, 0.f);
    }
  }
}

// K1: dual GEMM, M=64 (one b, 64 t's), FULL-K A-tile in LDS (fragment order,
// XOR-swizzled). 2 barriers total; k-loop barrier-free. 2KB-granule staging.
__global__ __launch_bounds__(512, 1)
void dual_gemm_kernel(const float* __restrict__ x,
                      const _Float16* __restrict__ WTf,
                      const float* __restrict__ bs,
                      const float* __restrict__ bv,
                      const float* __restrict__ q,
                      float* __restrict__ scores,
                      _Float16* __restrict__ vals_p) {
  __shared__ __align__(16) char A_lds[131072];  // 32ks x 4m x 64lane x 16B
  __shared__ float bk_s[ATT_DIM], bv_s[ATT_DIM], q_s[ATT_DIM];
  __shared__ float red_s[64];

  const int tid = threadIdx.x;
  const int blk = blockIdx.x;
  const int b = blk & 31;
  const int tc = blk >> 5;
  const int t0 = tc * 64;

  bk_s[tid] = bs[tid];
  bv_s[tid] = bv[tid];
  q_s[tid] = q[(size_t)b * ATT_DIM + tid];
  if (tid < 64) red_s[tid] = 0.f;

  const float* xb = x + (size_t)b * LIS_DIM;
  const int wv = tid >> 6;
  const int lane = tid & 63;
  const int lo = lane & 15;
  const int hi = lane >> 4;

  // stage addressing: iter i of half h covers idx = i*512+tid over 8192 f32x4
  auto st_load = [&](int h, int i) -> f32x4 {
    int idx = i * 512 + tid;
    int row = idx >> 7, c4 = idx & 127;
    return __builtin_nontemporal_load(
        (const f32x4*)(xb + (size_t)(t0 + row) * (B_DIM * LIS_DIM)) + h * 128 + c4);
  };
  auto st_write = [&](int h, int i, f32x4 v) {
    int idx = i * 512 + tid;
    int row = idx >> 7, c4 = idx & 127;
    int k = h * 512 + c4 * 4;
    int m = row >> 4, rlo = row & 15;
    int ks = k >> 5, khi = (k >> 3) & 3, j0 = k & 7;
    f16x4 hh;
    hh[0] = (_Float16)v[0]; hh[1] = (_Float16)v[1];
    hh[2] = (_Float16)v[2]; hh[3] = (_Float16)v[3];
    int byte = (((ks * 4 + m) * 64 + khi * 16 + rlo) * 16 + j0 * 2) ^
               (((ks & 7) ^ (khi << 1)) << 4);
    *(f16x4*)(A_lds + byte) = hh;
  };

  f32x4 kacc[4][4], vacc[4][4];
#pragma unroll
  for (int m = 0; m < 4; ++m)
#pragma unroll
    for (int n = 0; n < 4; ++n) {
      kacc[m][n] = (f32x4){0.f, 0.f, 0.f, 0.f};
      vacc[m][n] = (f32x4){0.f, 0.f, 0.f, 0.f};
    }

  // prologue: half 0, groups of 4 overlapped loads
  {
    f32x4 sl[4];
#pragma unroll
    for (int g = 0; g < 4; ++g) {
#pragma unroll
      for (int i = 0; i < 4; ++i) sl[i] = st_load(0, g * 4 + i);
#pragma unroll
      for (int i = 0; i < 4; ++i) st_write(0, g * 4 + i, sl[i]);
    }
  }
  __syncthreads();

  const f16x8* Wf = (const f16x8*)WTf;

  auto compute = [&](int ks) {
    f16x8 wkf[4], wvf[4], bx[4];
#pragma unroll
    for (int n = 0; n < 4; ++n) {
      wkf[n] = Wf[(size_t)((wv * 4 + n) * 32 + ks) * 64 + lane];
      wvf[n] = Wf[(size_t)((32 + wv * 4 + n) * 32 + ks) * 64 + lane];
    }
#pragma unroll
    for (int m = 0; m < 4; ++m) {
      int byte = (((ks * 4 + m) * 64 + lane) * 16) ^
                 (((ks & 7) ^ (hi << 1)) << 4);
      bx[m] = *(const f16x8*)(A_lds + byte);
    }
#pragma unroll
    for (int n = 0; n < 4; ++n)
#pragma unroll
      for (int m = 0; m < 4; ++m) {
        kacc[m][n] = __builtin_amdgcn_mfma_f32_16x16x32_f16(wkf[n], bx[m], kacc[m][n], 0, 0, 0);
        vacc[m][n] = __builtin_amdgcn_mfma_f32_16x16x32_f16(wvf[n], bx[m], vacc[m][n], 0, 0, 0);
      }
  };

  // ks 0..15: compute on half 0 while staging half 1 (4-deep load pipe)
  {
    f32x4 sl[4];
#pragma unroll
    for (int i = 0; i < 4; ++i) sl[i] = st_load(1, i);
#pragma unroll
    for (int ks = 0; ks < 16; ++ks) {
      st_write(1, ks, sl[ks & 3]);
      if (ks < 12) sl[ks & 3] = st_load(1, ks + 4);
      compute(ks);
    }
  }
  __syncthreads();
#pragma unroll
  for (int ks = 16; ks < 32; ++ks) compute(ks);

  // vals epilogue: packed lane-natural layout, non-temporal 8B stores
  _Float16* vp = vals_p + ((size_t)(b * 32 + tc) * 8 + wv) * 4096;
#pragma unroll
  for (int m = 0; m < 4; ++m)
#pragma unroll
    for (int n = 0; n < 4; ++n) {
      int col = wv * 64 + n * 16 + hi * 4;
      f16x4 h;
#pragma unroll
      for (int r = 0; r < 4; ++r)
        h[r] = (_Float16)fmaxf(vacc[m][n][r] + bv_s[col + r], 0.f);
      __builtin_nontemporal_store(h, (f16x4*)(vp + (m * 4 + n) * 256 + lane * 4));
    }

  // scores epilogue
  float sr[4] = {0.f, 0.f, 0.f, 0.f};
#pragma unroll
  for (int m = 0; m < 4; ++m)
#pragma unroll
    for (int n = 0; n < 4; ++n) {
      int col = wv * 64 + n * 16 + hi * 4;
#pragma unroll
      for (int r = 0; r < 4; ++r)
        sr[m] += q_s[col + r] * fmaxf(kacc[m][n][r] + bk_s[col + r], 0.f);
    }
#pragma unroll
  for (int m = 0; m < 4; ++m) {
    sr[m] += __shfl_xor(sr[m], 16, 64);
    sr[m] += __shfl_xor(sr[m], 32, 64);
    if (lane < 16) atomicAdd(&red_s[m * 16 + lo], sr[m]);
  }
  __syncthreads();
  if (tid < 64) scores[(size_t)b * T_DIM + t0 + tid] = red_s[tid];
}

// K2: masked softmax per b; writes attn f32 to out, zeroes context region of out
__global__ void softmax_kernel(const float* __restrict__ scores,
                               const int* __restrict__ llen,
                               float* __restrict__ attn_out,   // d_out + 16384
                               float* __restrict__ ctx_out) {  // d_out (zeroed here)
  __shared__ float rmax[4], rsum[4];
  int b = blockIdx.x, tid = threadIdx.x;
  int L = llen[b];
  float v[8];
  float mx = -1e30f;
  for (int i = 0; i < 8; ++i) {
    int t = i * 256 + tid;
    float s = scores[(size_t)b * T_DIM + t];
    if (t >= L) s -= 100.f;
    v[i] = s;
    mx = fmaxf(mx, s);
  }
  for (int d = 1; d < 64; d <<= 1) mx = fmaxf(mx, __shfl_xor(mx, d, 64));
  if ((tid & 63) == 0) rmax[tid >> 6] = mx;
  __syncthreads();
  mx = fmaxf(fmaxf(rmax[0], rmax[1]), fmaxf(rmax[2], rmax[3]));
  float sum = 0.f;
  for (int i = 0; i < 8; ++i) { v[i] = expf(v[i] - mx); sum += v[i]; }
  for (int d = 1; d < 64; d <<= 1) sum += __shfl_xor(sum, d, 64);
  if ((tid & 63) == 0) rsum[tid >> 6] = sum;
  __syncthreads();
  sum = rsum[0] + rsum[1] + rsum[2] + rsum[3];
  float inv = 1.f / sum;
  for (int i = 0; i < 8; ++i) {
    int t = i * 256 + tid;
    attn_out[(size_t)b * T_DIM + t] = v[i] * inv;
  }
  for (int i = tid; i < ATT_DIM; i += 256) ctx_out[(size_t)b * ATT_DIM + i] = 0.f;
}

// K3: ctx[b][col] = sum_t attn[b][t] * vals[t][col], decoding packed layout.
__global__ __launch_bounds__(512)
void ctx_kernel(const _Float16* __restrict__ vals_p,
                const float* __restrict__ attn,
                float* __restrict__ ctx) {
  __shared__ float attn_s[256];
  int blk = blockIdx.x;
  int b = blk >> 3, tcg = blk & 7;
  int tid = threadIdx.x;
  int wv = tid >> 6, lane = tid & 63, lo = lane & 15, hi = lane >> 4;
  if (tid < 256) attn_s[tid] = attn[(size_t)b * T_DIM + tcg * 256 + tid];
  __syncthreads();
  float cacc[4][4] = {};
  for (int i = 0; i < 4; ++i) {
    int tc = tcg * 4 + i;
    const _Float16* vp = vals_p + ((size_t)(b * 32 + tc) * 8 + wv) * 4096;
#pragma unroll
    for (int m = 0; m < 4; ++m) {
      float w = attn_s[i * 64 + m * 16 + lo];
#pragma unroll
      for (int n = 0; n < 4; ++n) {
        f16x4 v = __builtin_nontemporal_load(
            (const f16x4*)(vp + (m * 4 + n) * 256 + lane * 4));
#pragma unroll
        for (int r = 0; r < 4; ++r) cacc[n][r] += w * (float)v[r];
      }
    }
  }
#pragma unroll
  for (int n = 0; n < 4; ++n)
#pragma unroll
    for (int r = 0; r < 4; ++r) {
      float v = cacc[n][r];
      v += __shfl_xor(v, 1, 64);
      v += __shfl_xor(v, 2, 64);
      v += __shfl_xor(v, 4, 64);
      v += __shfl_xor(v, 8, 64);
      if (lo == 0)
        atomicAdd(&ctx[(size_t)b * ATT_DIM + wv * 64 + n * 16 + hi * 4 + r], v);
    }
}

extern "C" void kernel_launch(void* const* d_in, const int* in_sizes, int n_in,
                              void* d_out, int out_size, void* d_ws, size_t ws_size,
                              hipStream_t stream) {
  const float* x   = (const float*)d_in[0];
  const float* spe = (const float*)d_in[1];
  const int*   len = (const int*)d_in[2];
  const float* Ws  = (const float*)d_in[4];
  const float* bs  = (const float*)d_in[5];
  const float* Wv  = (const float*)d_in[6];
  const float* bv  = (const float*)d_in[7];
  const float* Wp  = (const float*)d_in[8];
  const float* bp  = (const float*)d_in[9];
  float* out = (float*)d_out;  // [0,16384): context f32, [16384,81920): attn f32

  char* ws = (char*)d_ws;
  _Float16* WTf  = (_Float16*)ws;                            // 2 MB packed frags
  float* q       = (float*)(ws + (2u << 20));                // 64 KB
  float* scores  = (float*)(ws + (2u << 20) + (64u << 10));  // 256 KB
  _Float16* vals = (_Float16*)(ws + (4u << 20));             // 64 MB packed

  prep_kernel<<<dim3(96), dim3(256), 0, stream>>>(Ws, Wv, WTf, spe, Wp, bp, q);
  dual_gemm_kernel<<<dim3(1024), dim3(512), 0, stream>>>(
      x, WTf, bs, bv, q, scores, vals);
  softmax_kernel<<<dim3(32), dim3(256), 0, stream>>>(scores, len, out + 16384, out);
  ctx_kernel<<<dim3(256), dim3(512), 0, stream>>>(vals, out + 16384, out);
}